// Round 1
// baseline (19715.024 us; speedup 1.0000x reference)
//
#include <hip/hip_runtime.h>
#include <math.h>

#define HH 1024
#define VV 4096
#define TSTEPS 128
#define NHYP 40   // B*K = 8*5

// ---------- helpers ----------

__device__ __forceinline__ float sigf(float x) { return 1.0f / (1.0f + expf(-x)); }

// sum across each 16-lane row via DPP (VALU pipe, no LDS). Row total lands in
// lane (row*16+15); other lanes hold prefixes.
__device__ __forceinline__ float rowsum16(float x) {
  x += __int_as_float(__builtin_amdgcn_update_dpp(0, __float_as_int(x), 0x111, 0xf, 0xf, true));
  x += __int_as_float(__builtin_amdgcn_update_dpp(0, __float_as_int(x), 0x112, 0xf, 0xf, true));
  x += __int_as_float(__builtin_amdgcn_update_dpp(0, __float_as_int(x), 0x114, 0xf, 0xf, true));
  x += __int_as_float(__builtin_amdgcn_update_dpp(0, __float_as_int(x), 0x118, 0xf, 0xf, true));
  return x;
}

// descending top-5 insert, tie -> lower flat index (matches jax.lax.top_k)
__device__ __forceinline__ void ins5(float* bv, int* bi, float v, int i) {
#pragma unroll
  for (int j = 0; j < 5; ++j) {
    if (v > bv[j] || (v == bv[j] && i < bi[j])) {
#pragma unroll
      for (int s = 4; s > j; --s) { bv[s] = bv[s - 1]; bi[s] = bi[s - 1]; }
      bv[j] = v; bi[j] = i;
      break;
    }
  }
}

// ---------- setup kernels ----------

__global__ void k_init(float* __restrict__ h0, float* __restrict__ c0,
                       float* __restrict__ hn0, float* __restrict__ cn0,
                       int* __restrict__ preds0, float* __restrict__ scores0,
                       int* __restrict__ tokens0, int* __restrict__ lens0,
                       int* __restrict__ par, int* __restrict__ blank) {
  int g = blockIdx.x * 256 + threadIdx.x;      // 64 blocks * 256
  for (int i = g; i < NHYP * HH; i += 64 * 256) { h0[i] = 0.f; c0[i] = 0.f; hn0[i] = 0.f; cn0[i] = 0.f; }
  if (g < NHYP * 128) preds0[g] = 0;
  if (g < NHYP) {
    scores0[g] = ((g % 5) == 0) ? 0.f : -1e9f;
    tokens0[g] = 0; lens0[g] = 0;
    par[g] = g; blank[g] = 1;                  // step-0 gather = identity into zeroed h_pre/c_pre
  }
}

// out[C][R] = in[R][C]
__global__ __launch_bounds__(256) void k_transp(const float* __restrict__ in,
                                                float* __restrict__ out, int R, int C) {
  __shared__ float tile[32][33];
  int c0 = blockIdx.x * 32, r0 = blockIdx.y * 32;
  int tx = threadIdx.x & 31, ty = threadIdx.x >> 5;   // ty 0..7
#pragma unroll
  for (int i = 0; i < 32; i += 8) tile[ty + i][tx] = in[(long)(r0 + ty + i) * C + c0 + tx];
  __syncthreads();
#pragma unroll
  for (int i = 0; i < 32; i += 8) out[(long)(c0 + ty + i) * R + r0 + tx] = tile[tx][ty + i];
}

// C[1024,1024] = A[1024,1024] @ B[1024,1024]   (tn_proj = tn_output @ W_tn)
__global__ __launch_bounds__(256) void k_tnproj(const float* __restrict__ A,
                                                const float* __restrict__ B,
                                                float* __restrict__ C) {
  __shared__ float As[64][20];
  __shared__ float Bs[16][68];
  int tid = threadIdx.x, blk = blockIdx.x;
  int bx = blk & 15, by = blk >> 4;
  int tx = tid & 15, ty = tid >> 4;
  float acc[4][4];
#pragma unroll
  for (int i = 0; i < 4; i++)
#pragma unroll
    for (int j = 0; j < 4; j++) acc[i][j] = 0.f;
  for (int k0 = 0; k0 < 1024; k0 += 16) {
    {
      int row = tid >> 2, q = tid & 3;
      float4 v = *(const float4*)&A[(long)(by * 64 + row) * 1024 + k0 + q * 4];
      As[row][q * 4] = v.x; As[row][q * 4 + 1] = v.y; As[row][q * 4 + 2] = v.z; As[row][q * 4 + 3] = v.w;
    }
    {
      int row = tid >> 4, q = tid & 15;
      float4 v = *(const float4*)&B[(long)(k0 + row) * 1024 + bx * 64 + q * 4];
      *(float4*)&Bs[row][q * 4] = v;
    }
    __syncthreads();
#pragma unroll
    for (int kk = 0; kk < 16; kk++) {
      float a0 = As[ty * 4][kk], a1 = As[ty * 4 + 1][kk], a2 = As[ty * 4 + 2][kk], a3 = As[ty * 4 + 3][kk];
      float4 b4 = *(const float4*)&Bs[kk][tx * 4];
      acc[0][0] += a0 * b4.x; acc[0][1] += a0 * b4.y; acc[0][2] += a0 * b4.z; acc[0][3] += a0 * b4.w;
      acc[1][0] += a1 * b4.x; acc[1][1] += a1 * b4.y; acc[1][2] += a1 * b4.z; acc[1][3] += a1 * b4.w;
      acc[2][0] += a2 * b4.x; acc[2][1] += a2 * b4.y; acc[2][2] += a2 * b4.z; acc[2][3] += a2 * b4.w;
      acc[3][0] += a3 * b4.x; acc[3][1] += a3 * b4.y; acc[3][2] += a3 * b4.z; acc[3][3] += a3 * b4.w;
    }
    __syncthreads();
  }
#pragma unroll
  for (int i = 0; i < 4; i++) {
    float4 v = make_float4(acc[i][0], acc[i][1], acc[i][2], acc[i][3]);
    *(float4*)&C[(long)(by * 64 + ty * 4 + i) * 1024 + bx * 64 + tx * 4] = v;
  }
}

// ---------- per-step kernels ----------

// K1: fused parent-gather + LSTM gates GEMM + cell pointwise.
// grid 256 blocks x 512 thr. block = (j16 in [0,64)) x (mg in [0,4)); wave w
// owns j-pair {j16*16+2w, +1}; lanes cover 256-wide K chunks (float4/lane).
__global__ __launch_bounds__(512) void k_gates(
    const float* __restrict__ E, const float* __restrict__ Wih, const float* __restrict__ Whh,
    const float* __restrict__ b_lstm,
    const int* __restrict__ tokens_in, const int* __restrict__ par, const int* __restrict__ blankf,
    const float* __restrict__ h_pre_in, const float* __restrict__ h_new_in,
    const float* __restrict__ c_pre_in, const float* __restrict__ c_new_in,
    float* __restrict__ h_pre_out, float* __restrict__ h_new_out,
    float* __restrict__ c_pre_out, float* __restrict__ c_new_out) {
  __shared__ float xs[2560];     // 10 rows x 256 (current K-chunk of emb or h)
  __shared__ float part[2560];   // 8 waves x 4 rowparts x 80 accs
  __shared__ int s_tok[10], s_par[10], s_blank[10];
  int tid = threadIdx.x, blk = blockIdx.x;
  int mg = blk & 3, j16 = blk >> 2;
  int m0 = mg * 10;
  if (tid < 10) { s_tok[tid] = tokens_in[m0 + tid]; s_par[tid] = par[m0 + tid]; s_blank[tid] = blankf[m0 + tid]; }

  float acc[80];
#pragma unroll
  for (int a = 0; a < 80; a++) acc[a] = 0.f;
  int wav = tid >> 6, lane = tid & 63;

  for (int c = 0; c < 8; c++) {                 // 4 emb chunks then 4 h chunks
    const float* Wm = (c < 4) ? Wih : Whh;
    int kc = (c & 3) * 256;
    float4 w[2][4];
#pragma unroll
    for (int jj = 0; jj < 2; jj++)
#pragma unroll
      for (int g = 0; g < 4; g++) {
        int row = g * HH + j16 * 16 + wav * 2 + jj;
        w[jj][g] = *(const float4*)&Wm[(long)row * HH + kc + lane * 4];
      }
    __syncthreads();                            // xs free from previous readers
    for (int f = tid; f < 640; f += 512) {
      int m = f >> 6, k4 = (f & 63) * 4;
      float4 v;
      if (c < 4) v = *(const float4*)&E[(long)s_tok[m] * HH + kc + k4];
      else {
        const float* hb = s_blank[m] ? h_pre_in : h_new_in;
        v = *(const float4*)&hb[(long)s_par[m] * HH + kc + k4];
      }
      *(float4*)&xs[f * 4] = v;
      if (c >= 4 && j16 == 0) *(float4*)&h_pre_out[(long)(m0 + m) * HH + kc + k4] = v;  // materialize gathered h
    }
    __syncthreads();
#pragma unroll
    for (int m = 0; m < 10; m++) {
      float4 x = *(const float4*)&xs[m * 256 + lane * 4];
#pragma unroll
      for (int jj = 0; jj < 2; jj++)
#pragma unroll
        for (int g = 0; g < 4; g++) {
          float4 ww = w[jj][g];
          int a = jj * 40 + m * 4 + g;
          acc[a] += x.x * ww.x; acc[a] += x.y * ww.y; acc[a] += x.z * ww.z; acc[a] += x.w * ww.w;
        }
    }
  }
#pragma unroll
  for (int a = 0; a < 80; a++) acc[a] = rowsum16(acc[a]);
  __syncthreads();
  if ((lane & 15) == 15) {
    int r = lane >> 4;
    float* p = &part[(wav * 4 + r) * 80];
#pragma unroll
    for (int a = 0; a < 80; a += 4) *(float4*)&p[a] = make_float4(acc[a], acc[a + 1], acc[a + 2], acc[a + 3]);
  }
  __syncthreads();
  if (tid < 160) {                              // cells m-major for coalesced stores
    int m = tid >> 4, jloc = tid & 15;
    int w_ = jloc >> 1, jj = jloc & 1;
    float gi = 0, gf = 0, gg = 0, go = 0;
#pragma unroll
    for (int r = 0; r < 4; r++) {
      const float* p = &part[(w_ * 4 + r) * 80 + jj * 40 + m * 4];
      gi += p[0]; gf += p[1]; gg += p[2]; go += p[3];
    }
    int j = j16 * 16 + w_ * 2 + jj;
    int mglob = m0 + m;
    gi += b_lstm[j]; gf += b_lstm[HH + j]; gg += b_lstm[2 * HH + j]; go += b_lstm[3 * HH + j];
    const float* cb = s_blank[m] ? c_pre_in : c_new_in;
    float csel = cb[(long)s_par[m] * HH + j];
    float cn = sigf(gf) * csel + sigf(gi) * tanhf(gg);
    float hn = sigf(go) * tanhf(cn);
    long o = (long)mglob * HH + j;
    h_new_out[o] = hn; c_new_out[o] = cn; c_pre_out[o] = csel;   // materialize gathered c
  }
}

// K2: joint = tanh(tn_proj[b,t,:] + h_new @ W_pn + b_joint)
// grid 256 x 256 thr. block = d16 x mg; wave owns 4 d-rows.
__global__ __launch_bounds__(256) void k_joint(
    const float* __restrict__ h_new_cur, const float* __restrict__ WpnT,
    const float* __restrict__ tn_proj, const float* __restrict__ b_joint,
    float* __restrict__ joint, int tstep) {
  __shared__ float xs[2560];
  __shared__ float part[640];
  int tid = threadIdx.x, blk = blockIdx.x;
  int mg = blk & 3, d16 = blk >> 2, m0 = mg * 10;
  float acc[40];
#pragma unroll
  for (int a = 0; a < 40; a++) acc[a] = 0.f;
  int wav = tid >> 6, lane = tid & 63;
  for (int c = 0; c < 4; c++) {
    int kc = c * 256;
    float4 w[4];
#pragma unroll
    for (int dd = 0; dd < 4; dd++) {
      int row = d16 * 16 + wav * 4 + dd;
      w[dd] = *(const float4*)&WpnT[(long)row * HH + kc + lane * 4];
    }
    __syncthreads();
    for (int f = tid; f < 640; f += 256) {
      int m = f >> 6, k4 = (f & 63) * 4;
      *(float4*)&xs[f * 4] = *(const float4*)&h_new_cur[(long)(m0 + m) * HH + kc + k4];
    }
    __syncthreads();
#pragma unroll
    for (int m = 0; m < 10; m++) {
      float4 x = *(const float4*)&xs[m * 256 + lane * 4];
#pragma unroll
      for (int dd = 0; dd < 4; dd++) {
        float4 ww = w[dd]; int a = dd * 10 + m;
        acc[a] += x.x * ww.x; acc[a] += x.y * ww.y; acc[a] += x.z * ww.z; acc[a] += x.w * ww.w;
      }
    }
  }
#pragma unroll
  for (int a = 0; a < 40; a++) acc[a] = rowsum16(acc[a]);
  __syncthreads();
  if ((lane & 15) == 15) {
    int r = lane >> 4;
    float* p = &part[(wav * 4 + r) * 40];
#pragma unroll
    for (int a = 0; a < 40; a += 4) *(float4*)&p[a] = make_float4(acc[a], acc[a + 1], acc[a + 2], acc[a + 3]);
  }
  __syncthreads();
  if (tid < 160) {
    int m = tid >> 4, dloc = tid & 15, w_ = dloc >> 2, dd = dloc & 3;
    float s = 0;
#pragma unroll
    for (int r = 0; r < 4; r++) s += part[(w_ * 4 + r) * 40 + dd * 10 + m];
    int d = d16 * 16 + w_ * 4 + dd;
    int mglob = m0 + m, b = mglob / 5;
    float val = s + tn_proj[((long)b * TSTEPS + tstep) * HH + d] + b_joint[d];
    joint[(long)mglob * HH + d] = tanhf(val);
  }
}

// K3: logits = joint @ W_out + b_out, plus deterministic per-(m, v64-block)
// exp-sum partials (tanh-bounded logits -> max-free logsumexp is safe).
// grid 256 x 512 thr. block = v64 x mg; wave owns 8 v-rows.
__global__ __launch_bounds__(512) void k_logits(
    const float* __restrict__ joint, const float* __restrict__ WoutT,
    const float* __restrict__ b_out,
    float* __restrict__ logits, float* __restrict__ expsum_part) {
  __shared__ float xs[2560];
  __shared__ float part[2560];
  __shared__ float esum[10];
  int tid = threadIdx.x, blk = blockIdx.x;
  int mg = blk & 3, v64 = blk >> 2, m0 = mg * 10;
  if (tid < 10) esum[tid] = 0.f;
  float acc[80];
#pragma unroll
  for (int a = 0; a < 80; a++) acc[a] = 0.f;
  int wav = tid >> 6, lane = tid & 63;
  for (int c = 0; c < 4; c++) {
    int kc = c * 256;
    float4 w[8];
#pragma unroll
    for (int vv = 0; vv < 8; vv++) {
      int row = v64 * 64 + wav * 8 + vv;
      w[vv] = *(const float4*)&WoutT[(long)row * HH + kc + lane * 4];
    }
    __syncthreads();
    for (int f = tid; f < 640; f += 512) {
      int m = f >> 6, k4 = (f & 63) * 4;
      *(float4*)&xs[f * 4] = *(const float4*)&joint[(long)(m0 + m) * HH + kc + k4];
    }
    __syncthreads();
#pragma unroll
    for (int m = 0; m < 10; m++) {
      float4 x = *(const float4*)&xs[m * 256 + lane * 4];
#pragma unroll
      for (int vv = 0; vv < 8; vv++) {
        float4 ww = w[vv]; int a = vv * 10 + m;
        acc[a] += x.x * ww.x; acc[a] += x.y * ww.y; acc[a] += x.z * ww.z; acc[a] += x.w * ww.w;
      }
    }
  }
#pragma unroll
  for (int a = 0; a < 80; a++) acc[a] = rowsum16(acc[a]);
  __syncthreads();
  if ((lane & 15) == 15) {
    int r = lane >> 4;
    float* p = &part[(wav * 4 + r) * 80];
#pragma unroll
    for (int a = 0; a < 80; a += 4) *(float4*)&p[a] = make_float4(acc[a], acc[a + 1], acc[a + 2], acc[a + 3]);
  }
  __syncthreads();
  for (int cell = tid; cell < 640; cell += 512) {   // m-major: coalesced stores, 16-lane rows share m
    int m = cell >> 6, vloc = cell & 63, w_ = vloc >> 3, vv = vloc & 7;
    float s = 0;
#pragma unroll
    for (int r = 0; r < 4; r++) s += part[(w_ * 4 + r) * 80 + vv * 10 + m];
    int v = v64 * 64 + vloc;
    int mglob = m0 + m;
    float lg = s + b_out[v];
    logits[(long)mglob * VV + v] = lg;
    float e = expf(lg);
    e = rowsum16(e);
    if ((tid & 15) == 15) atomicAdd(&esum[m], e);
  }
  __syncthreads();
  if (tid < 10) expsum_part[(m0 + tid) * 64 + v64] = esum[tid];
}

// K4: per-batch top-5 over K*V candidates + beam-state update. grid 8 x 256.
__global__ __launch_bounds__(256) void k_topk(
    const float* __restrict__ logits, const float* __restrict__ expsum_part,
    const float* __restrict__ scores_in, const int* __restrict__ tokens_in,
    const int* __restrict__ lens_in, const int* __restrict__ preds_in,
    float* __restrict__ scores_out, int* __restrict__ tokens_out,
    int* __restrict__ lens_out, int* __restrict__ preds_out,
    int* __restrict__ par, int* __restrict__ blankf) {
  __shared__ float sc_ls[5];
  __shared__ float pv[1280];
  __shared__ int pi[1280];
  __shared__ float outv[5];
  __shared__ int outi[5];
  __shared__ int s_kp[5], s_tok[5], s_blank[5], s_len[5];
  int b = blockIdx.x, tid = threadIdx.x;
  if (tid < 5) {
    const float* ep = &expsum_part[(b * 5 + tid) * 64];
    float s = 0;
#pragma unroll
    for (int i = 0; i < 64; i++) s += ep[i];
    sc_ls[tid] = scores_in[b * 5 + tid] - logf(s);
  }
  __syncthreads();
  float bv[5]; int bi[5];
#pragma unroll
  for (int j = 0; j < 5; j++) { bv[j] = -3.0e38f; bi[j] = 0x7fffffff; }
  const float4* lg4 = (const float4*)&logits[(long)b * 5 * VV];
  for (int f = tid; f < 5120; f += 256) {
    float4 v = lg4[f];
    float base = sc_ls[f >> 10];
    int i0 = f * 4;
    ins5(bv, bi, v.x + base, i0);
    ins5(bv, bi, v.y + base, i0 + 1);
    ins5(bv, bi, v.z + base, i0 + 2);
    ins5(bv, bi, v.w + base, i0 + 3);
  }
#pragma unroll
  for (int j = 0; j < 5; j++) { pv[tid * 5 + j] = bv[j]; pi[tid * 5 + j] = bi[j]; }
  __syncthreads();
  if (tid < 64) {
    for (int srcT = tid + 64; srcT < 256; srcT += 64)
#pragma unroll
      for (int j = 0; j < 5; j++) ins5(bv, bi, pv[srcT * 5 + j], pi[srcT * 5 + j]);
    for (int r = 0; r < 5; r++) {
      float mv = bv[0]; int mi = bi[0];
#pragma unroll
      for (int off = 32; off >= 1; off >>= 1) {
        float ov = __shfl_xor(mv, off, 64);
        int oi = __shfl_xor(mi, off, 64);
        if (ov > mv || (ov == mv && oi < mi)) { mv = ov; mi = oi; }
      }
      if (bv[0] == mv && bi[0] == mi) {   // this lane owned the winner: pop
        bv[0] = bv[1]; bi[0] = bi[1]; bv[1] = bv[2]; bi[1] = bi[2];
        bv[2] = bv[3]; bi[2] = bi[3]; bv[3] = bv[4]; bi[3] = bi[4];
        bv[4] = -3.0e38f; bi[4] = 0x7fffffff;
      }
      if (tid == 0) { outv[r] = mv; outi[r] = mi; }
    }
  }
  __syncthreads();
  if (tid == 0) {
    for (int j = 0; j < 5; j++) {
      int idx = outi[j], kp = idx >> 12, tok = idx & 4095;
      int isb = (tok == 0) ? 1 : 0;
      int p_ = b * 5 + kp;
      scores_out[b * 5 + j] = outv[j];
      par[b * 5 + j] = p_;
      blankf[b * 5 + j] = isb;
      tokens_out[b * 5 + j] = isb ? tokens_in[p_] : tok;
      int lp = lens_in[p_];
      lens_out[b * 5 + j] = lp + (isb ? 0 : 1);
      s_kp[j] = p_; s_tok[j] = tok; s_blank[j] = isb; s_len[j] = lp;
    }
  }
  __syncthreads();
  for (int cell = tid; cell < 640; cell += 256) {
    int j = cell >> 7, pos = cell & 127;
    int v = preds_in[s_kp[j] * 128 + pos];
    if (!s_blank[j] && pos == s_len[j]) v = s_tok[j];
    preds_out[(b * 5 + j) * 128 + pos] = v;
  }
}

// final: norm, argmax per batch (tie->first), outputs
__global__ void k_final(const float* __restrict__ scores, const int* __restrict__ lens,
                        const int* __restrict__ preds, float* __restrict__ out) {
  __shared__ int s_best[8];
  __shared__ float s_maxn[8];
  int tid = threadIdx.x;
  if (tid < 40) out[1033 + tid] = scores[tid] / (float)(lens[tid] + 1);
  if (tid < 8) {
    float bvn = -3e38f; int bk = 0;
    for (int k = 0; k < 5; k++) {
      float n = scores[tid * 5 + k] / (float)(lens[tid * 5 + k] + 1);
      if (n > bvn) { bvn = n; bk = k; }
    }
    s_best[tid] = bk; s_maxn[tid] = bvn;
    out[1024 + tid] = (float)lens[tid * 5 + bk];
  }
  __syncthreads();
  if (tid == 0) {
    float s = 0;
    for (int b = 0; b < 8; b++) s += expf(s_maxn[b]);
    out[1032] = s / 8.f;
  }
  for (int c = tid; c < 1024; c += 256) {
    int b = c >> 7, pos = c & 127;
    out[c] = (float)preds[(b * 5 + s_best[b]) * 128 + pos];
  }
}

// ---------- launch ----------

extern "C" void kernel_launch(void* const* d_in, const int* in_sizes, int n_in,
                              void* d_out, int out_size, void* d_ws, size_t ws_size,
                              hipStream_t stream) {
  const float* tn   = (const float*)d_in[0];
  const float* E    = (const float*)d_in[1];
  const float* Wih  = (const float*)d_in[2];
  const float* Whh  = (const float*)d_in[3];
  const float* bl   = (const float*)d_in[4];
  const float* Wtn  = (const float*)d_in[5];
  const float* Wpn  = (const float*)d_in[6];
  const float* bj   = (const float*)d_in[7];
  const float* Wout = (const float*)d_in[8];
  const float* bo   = (const float*)d_in[9];
  float* out = (float*)d_out;

  float* w = (float*)d_ws;
  size_t off = 0;
  float* tn_proj = w + off; off += 1048576;
  float* WpnT    = w + off; off += 1048576;
  float* WoutT   = w + off; off += 4194304;
  float* joint   = w + off; off += 40960;
  float* logits  = w + off; off += 163840;
  float* expp    = w + off; off += 2560;
  float* h_pre[2] = { w + off, w + off + 40960 }; off += 81920;
  float* c_pre[2] = { w + off, w + off + 40960 }; off += 81920;
  float* h_new[2] = { w + off, w + off + 40960 }; off += 81920;
  float* c_new[2] = { w + off, w + off + 40960 }; off += 81920;
  float* scores[2] = { w + off, w + off + 40 }; off += 80;
  int* ib = (int*)(w + off);
  int* tokens[2] = { ib, ib + 40 }; ib += 80;
  int* lens[2]   = { ib, ib + 40 }; ib += 80;
  int* par = ib; ib += 40;
  int* blank = ib; ib += 40;
  int* preds[2] = { ib, ib + 5120 }; ib += 10240;
  if (ws_size < (off + 10480) * 4) return;   // 27.35 MB needed

  k_init<<<64, 256, 0, stream>>>(h_pre[0], c_pre[0], h_new[0], c_new[0],
                                 preds[0], scores[0], tokens[0], lens[0], par, blank);
  k_transp<<<dim3(32, 32), 256, 0, stream>>>(Wpn, WpnT, 1024, 1024);
  k_transp<<<dim3(128, 32), 256, 0, stream>>>(Wout, WoutT, 1024, 4096);
  k_tnproj<<<256, 256, 0, stream>>>(tn, Wtn, tn_proj);

  for (int t = 0; t < TSTEPS; t++) {
    int pin = t & 1, po = 1 - pin;
    k_gates<<<256, 512, 0, stream>>>(E, Wih, Whh, bl, tokens[pin], par, blank,
                                     h_pre[pin], h_new[pin], c_pre[pin], c_new[pin],
                                     h_pre[po], h_new[po], c_pre[po], c_new[po]);
    k_joint<<<256, 256, 0, stream>>>(h_new[po], WpnT, tn_proj, bj, joint, t);
    k_logits<<<256, 512, 0, stream>>>(joint, WoutT, bo, logits, expp);
    k_topk<<<8, 256, 0, stream>>>(logits, expp, scores[pin], tokens[pin], lens[pin], preds[pin],
                                  scores[po], tokens[po], lens[po], preds[po], par, blank);
  }
  k_final<<<1, 256, 0, stream>>>(scores[0], lens[0], preds[0], out);
}

// Round 2
// 18342.624 us; speedup vs baseline: 1.0748x; 1.0748x over previous
//
#include <hip/hip_runtime.h>
#include <math.h>

#define HH 1024
#define VV 4096
#define TSTEPS 128
#define NB 256
#define NT 512

// ---------- helpers ----------

__device__ __forceinline__ float sigf(float x) { return 1.0f / (1.0f + expf(-x)); }

// sum across each 16-lane row via DPP; row total lands in lane (row*16+15).
__device__ __forceinline__ float rowsum16(float x) {
  x += __int_as_float(__builtin_amdgcn_update_dpp(0, __float_as_int(x), 0x111, 0xf, 0xf, true));
  x += __int_as_float(__builtin_amdgcn_update_dpp(0, __float_as_int(x), 0x112, 0xf, 0xf, true));
  x += __int_as_float(__builtin_amdgcn_update_dpp(0, __float_as_int(x), 0x114, 0xf, 0xf, true));
  x += __int_as_float(__builtin_amdgcn_update_dpp(0, __float_as_int(x), 0x118, 0xf, 0xf, true));
  return x;
}

// descending top-5 insert, tie -> lower flat index (matches jax.lax.top_k)
__device__ __forceinline__ void ins5(float* bv, int* bi, float v, int i) {
#pragma unroll
  for (int j = 0; j < 5; ++j) {
    if (v > bv[j] || (v == bv[j] && i < bi[j])) {
#pragma unroll
      for (int s = 4; s > j; --s) { bv[s] = bv[s - 1]; bi[s] = bi[s - 1]; }
      bv[j] = v; bi[j] = i;
      break;
    }
  }
}

// ---------- setup kernels ----------

// out[C][R] = in[R][C]
__global__ __launch_bounds__(256) void k_transp(const float* __restrict__ in,
                                                float* __restrict__ out, int R, int C) {
  __shared__ float tile[32][33];
  int c0 = blockIdx.x * 32, r0 = blockIdx.y * 32;
  int tx = threadIdx.x & 31, ty = threadIdx.x >> 5;
#pragma unroll
  for (int i = 0; i < 32; i += 8) tile[ty + i][tx] = in[(long)(r0 + ty + i) * C + c0 + tx];
  __syncthreads();
#pragma unroll
  for (int i = 0; i < 32; i += 8) out[(long)(c0 + ty + i) * R + r0 + tx] = tile[tx][ty + i];
}

// C[1024,1024] = A[1024,1024] @ B[1024,1024]   (tn_proj = tn_output @ W_tn)
__global__ __launch_bounds__(256) void k_tnproj(const float* __restrict__ A,
                                                const float* __restrict__ B,
                                                float* __restrict__ C) {
  __shared__ float As[64][20];
  __shared__ float Bs[16][68];
  int tid = threadIdx.x, blk = blockIdx.x;
  int bx = blk & 15, by = blk >> 4;
  int tx = tid & 15, ty = tid >> 4;
  float acc[4][4];
#pragma unroll
  for (int i = 0; i < 4; i++)
#pragma unroll
    for (int j = 0; j < 4; j++) acc[i][j] = 0.f;
  for (int k0 = 0; k0 < 1024; k0 += 16) {
    {
      int row = tid >> 2, q = tid & 3;
      float4 v = *(const float4*)&A[(long)(by * 64 + row) * 1024 + k0 + q * 4];
      As[row][q * 4] = v.x; As[row][q * 4 + 1] = v.y; As[row][q * 4 + 2] = v.z; As[row][q * 4 + 3] = v.w;
    }
    {
      int row = tid >> 4, q = tid & 15;
      float4 v = *(const float4*)&B[(long)(k0 + row) * 1024 + bx * 64 + q * 4];
      *(float4*)&Bs[row][q * 4] = v;
    }
    __syncthreads();
#pragma unroll
    for (int kk = 0; kk < 16; kk++) {
      float a0 = As[ty * 4][kk], a1 = As[ty * 4 + 1][kk], a2 = As[ty * 4 + 2][kk], a3 = As[ty * 4 + 3][kk];
      float4 b4 = *(const float4*)&Bs[kk][tx * 4];
      acc[0][0] += a0 * b4.x; acc[0][1] += a0 * b4.y; acc[0][2] += a0 * b4.z; acc[0][3] += a0 * b4.w;
      acc[1][0] += a1 * b4.x; acc[1][1] += a1 * b4.y; acc[1][2] += a1 * b4.z; acc[1][3] += a1 * b4.w;
      acc[2][0] += a2 * b4.x; acc[2][1] += a2 * b4.y; acc[2][2] += a2 * b4.z; acc[2][3] += a2 * b4.w;
      acc[3][0] += a3 * b4.x; acc[3][1] += a3 * b4.y; acc[3][2] += a3 * b4.z; acc[3][3] += a3 * b4.w;
    }
    __syncthreads();
  }
#pragma unroll
  for (int i = 0; i < 4; i++) {
    float4 v = make_float4(acc[i][0], acc[i][1], acc[i][2], acc[i][3]);
    *(float4*)&C[(long)(by * 64 + ty * 4 + i) * 1024 + bx * 64 + tx * 4] = v;
  }
}

// ---------- persistent megakernel ----------
// 256 blocks x 512 thr, cooperative. Per step: gates -> gsync -> joint -> gsync
// -> logits(+local top5 + expsum partials) -> gsync; beam update is recomputed
// redundantly by every block at the start of the next gates phase.

__global__ __launch_bounds__(NT, 2) void k_beam(
    const float* __restrict__ E, const float* __restrict__ Wih,
    const float* __restrict__ Whh, const float* __restrict__ b_lstm,
    const float* __restrict__ tn_proj, const float* __restrict__ WpnT,
    const float* __restrict__ b_joint, const float* __restrict__ WoutT,
    const float* __restrict__ b_out,
    float* __restrict__ h_pre0, float* __restrict__ h_pre1,
    float* __restrict__ c_pre0, float* __restrict__ c_pre1,
    float* __restrict__ h_new0, float* __restrict__ h_new1,
    float* __restrict__ c_new0, float* __restrict__ c_new1,
    float* __restrict__ joint, float* __restrict__ expsum_part,
    float* __restrict__ top5v, int* __restrict__ top5i,
    int* __restrict__ preds0, int* __restrict__ preds1,
    float* __restrict__ gscores, int* __restrict__ glens,
    unsigned int* bar, float* __restrict__ out) {
  int tid = threadIdx.x, blk = blockIdx.x;
  int mg = blk & 3, sec = blk >> 2, m0 = mg * 10;
  int wav = tid >> 6, lane = tid & 63;

  __shared__ float xs[2560];
  __shared__ float part[2560];
  __shared__ float s_scores[10], s_scls[10], ns[10];
  __shared__ int s_tokens[10], s_lens[10], s_par[10], s_blank[10];
  __shared__ int ntok[10], nlen[10], npar[10], nblank[10];
  __shared__ float esl[10][4];
  __shared__ int s_best[8];
  __shared__ float s_maxn[8];

  if (tid < 10) {
    s_scores[tid] = ((tid % 5) == 0) ? 0.f : -1e9f;
    s_tokens[tid] = 0; s_lens[tid] = 0; s_par[tid] = m0 + tid; s_blank[tid] = 1;
  }
  if (blk < 4)
    for (int i = tid; i < 1280; i += NT) preds0[m0 * 128 + i] = 0;
  __syncthreads();

  unsigned int target = 0;
  auto gsync = [&]() {
    __syncthreads();
    if (tid == 0) {
      target += NB;
      __threadfence();   // release: drain stores, wb L2 to LLC
      __hip_atomic_fetch_add(bar, 1u, __ATOMIC_RELAXED, __HIP_MEMORY_SCOPE_AGENT);
      while (__hip_atomic_load(bar, __ATOMIC_RELAXED, __HIP_MEMORY_SCOPE_AGENT) < target)
        __builtin_amdgcn_s_sleep(1);
      __threadfence();   // acquire: invalidate L1/L2
    }
    __syncthreads();
  };

  // beam update #u (u in 1..128): consumes phase-L outputs of step u-1.
  auto beam_update = [&](int u) {
    if (tid < 10) {
      const float* ep = &expsum_part[(m0 + tid) * 64];
      float ssum = 0.f;
#pragma unroll
      for (int i = 0; i < 64; i++) ssum += ep[i];
      s_scls[tid] = s_scores[tid] - logf(ssum);
    }
    __syncthreads();
    if (wav < 2) {                      // wave 0 -> batch 2mg, wave 1 -> batch 2mg+1
      float bv[5]; int bi[5];
#pragma unroll
      for (int j = 0; j < 5; j++) { bv[j] = -3.0e38f; bi[j] = 0x7fffffff; }
      for (int L = lane; L < 320; L += 64) {
        int kp = L >> 6, v64i = L & 63;
        float base = s_scls[wav * 5 + kp];
        int off = ((m0 + wav * 5 + kp) * 64 + v64i) * 5;
#pragma unroll
        for (int j = 0; j < 5; j++) ins5(bv, bi, top5v[off + j] + base, top5i[off + j]);
      }
      float myv = 0.f; int myi = 0;
#pragma unroll
      for (int r = 0; r < 5; r++) {
        float mv = bv[0]; int mi = bi[0];
#pragma unroll
        for (int off2 = 1; off2 < 64; off2 <<= 1) {
          float ov = __shfl_xor(mv, off2, 64);
          int oi = __shfl_xor(mi, off2, 64);
          if (ov > mv || (ov == mv && oi < mi)) { mv = ov; mi = oi; }
        }
        if (bv[0] == mv && bi[0] == mi) {   // owner pops
          bv[0] = bv[1]; bi[0] = bi[1]; bv[1] = bv[2]; bi[1] = bi[2];
          bv[2] = bv[3]; bi[2] = bi[3]; bv[3] = bv[4]; bi[3] = bi[4];
          bv[4] = -3.0e38f; bi[4] = 0x7fffffff;
        }
        if (lane == r) { myv = mv; myi = mi; }
      }
      if (lane < 5) {
        int idx = myi;
        int kp = idx >> 12, tok = idx & 4095;
        int isb = (tok == 0) ? 1 : 0;
        int ploc = wav * 5 + kp, slot = wav * 5 + lane;
        ns[slot] = myv;
        npar[slot] = m0 + ploc;
        nblank[slot] = isb;
        ntok[slot] = isb ? s_tokens[ploc] : tok;
        nlen[slot] = s_lens[ploc] + (isb ? 0 : 1);
      }
    }
    __syncthreads();
    if (tid < 10) {
      s_scores[tid] = ns[tid]; s_tokens[tid] = ntok[tid]; s_lens[tid] = nlen[tid];
      s_par[tid] = npar[tid]; s_blank[tid] = nblank[tid];
    }
    __syncthreads();
    if (blk < 4) {                       // exclusive owners of preds rows m0..m0+9
      const int* pip = ((u - 1) & 1) ? preds1 : preds0;
      int* pop = (u & 1) ? preds1 : preds0;
      for (int cell = tid; cell < 1280; cell += NT) {
        int j = cell >> 7, pos = cell & 127;
        int isb = s_blank[j];
        int plen = s_lens[j] - (isb ? 0 : 1);
        int v = pip[s_par[j] * 128 + pos];
        if (!isb && pos == plen) v = s_tokens[j];
        pop[(m0 + j) * 128 + pos] = v;
      }
    }
  };

  for (int t = 0; t < TSTEPS; ++t) {
    if (t > 0) beam_update(t);
    const float* h_pre_in = (t & 1) ? h_pre1 : h_pre0;
    const float* h_new_in = (t & 1) ? h_new1 : h_new0;
    const float* c_pre_in = (t & 1) ? c_pre1 : c_pre0;
    const float* c_new_in = (t & 1) ? c_new1 : c_new0;
    float* h_pre_o = (t & 1) ? h_pre0 : h_pre1;
    float* h_new_o = (t & 1) ? h_new0 : h_new1;
    float* c_pre_o = (t & 1) ? c_pre0 : c_pre1;
    float* c_new_o = (t & 1) ? c_new0 : c_new1;

    // ---- phase G: gather + LSTM gates + cell ----
    {
      int j16 = sec;
      float acc[80];
#pragma unroll
      for (int a = 0; a < 80; a++) acc[a] = 0.f;
      for (int c = 0; c < 8; c++) {
        const float* Wm = (c < 4) ? Wih : Whh;
        int kc = (c & 3) * 256;
        float4 w[2][4];
#pragma unroll
        for (int jj = 0; jj < 2; jj++)
#pragma unroll
          for (int g = 0; g < 4; g++) {
            int row = g * HH + j16 * 16 + wav * 2 + jj;
            w[jj][g] = *(const float4*)&Wm[(long)row * HH + kc + lane * 4];
          }
        __syncthreads();
        for (int f = tid; f < 640; f += NT) {
          int m = f >> 6, k4 = (f & 63) * 4;
          float4 v;
          if (c < 4) v = *(const float4*)&E[(long)s_tokens[m] * HH + kc + k4];
          else if (t == 0) v = make_float4(0.f, 0.f, 0.f, 0.f);
          else {
            const float* hb = s_blank[m] ? h_pre_in : h_new_in;
            v = *(const float4*)&hb[(long)s_par[m] * HH + kc + k4];
          }
          *(float4*)&xs[f * 4] = v;
          if (c >= 4 && j16 == 0) *(float4*)&h_pre_o[(long)(m0 + m) * HH + kc + k4] = v;
        }
        __syncthreads();
#pragma unroll
        for (int m = 0; m < 10; m++) {
          float4 x = *(const float4*)&xs[m * 256 + lane * 4];
#pragma unroll
          for (int jj = 0; jj < 2; jj++)
#pragma unroll
            for (int g = 0; g < 4; g++) {
              float4 ww = w[jj][g];
              int a = jj * 40 + m * 4 + g;
              acc[a] += x.x * ww.x; acc[a] += x.y * ww.y; acc[a] += x.z * ww.z; acc[a] += x.w * ww.w;
            }
        }
      }
#pragma unroll
      for (int a = 0; a < 80; a++) acc[a] = rowsum16(acc[a]);
      __syncthreads();
      if ((lane & 15) == 15) {
        int r = lane >> 4;
        float* p = &part[(wav * 4 + r) * 80];
#pragma unroll
        for (int a = 0; a < 80; a += 4) *(float4*)&p[a] = make_float4(acc[a], acc[a + 1], acc[a + 2], acc[a + 3]);
      }
      __syncthreads();
      if (tid < 160) {
        int m = tid >> 4, jloc = tid & 15;
        int w_ = jloc >> 1, jj = jloc & 1;
        float gi = 0, gf = 0, gg = 0, go = 0;
#pragma unroll
        for (int r = 0; r < 4; r++) {
          const float* p = &part[(w_ * 4 + r) * 80 + jj * 40 + m * 4];
          gi += p[0]; gf += p[1]; gg += p[2]; go += p[3];
        }
        int j = j16 * 16 + jloc;
        gi += b_lstm[j]; gf += b_lstm[HH + j]; gg += b_lstm[2 * HH + j]; go += b_lstm[3 * HH + j];
        float csel;
        if (t == 0) csel = 0.f;
        else {
          const float* cb = s_blank[m] ? c_pre_in : c_new_in;
          csel = cb[(long)s_par[m] * HH + j];
        }
        float cn = sigf(gf) * csel + sigf(gi) * tanhf(gg);
        float hn = sigf(go) * tanhf(cn);
        long o = (long)(m0 + m) * HH + j;
        h_new_o[o] = hn; c_new_o[o] = cn; c_pre_o[o] = csel;
      }
    }
    gsync();

    // ---- phase J: joint = tanh(tn + h_new @ W_pn + b) ----
    {
      int d16 = sec;
      float acc[20];
#pragma unroll
      for (int a = 0; a < 20; a++) acc[a] = 0.f;
      for (int c = 0; c < 4; c++) {
        int kc = c * 256;
        float4 w[2];
#pragma unroll
        for (int dd = 0; dd < 2; dd++) {
          int row = d16 * 16 + wav * 2 + dd;
          w[dd] = *(const float4*)&WpnT[(long)row * HH + kc + lane * 4];
        }
        __syncthreads();
        for (int f = tid; f < 640; f += NT) {
          int m = f >> 6, k4 = (f & 63) * 4;
          *(float4*)&xs[f * 4] = *(const float4*)&h_new_o[(long)(m0 + m) * HH + kc + k4];
        }
        __syncthreads();
#pragma unroll
        for (int m = 0; m < 10; m++) {
          float4 x = *(const float4*)&xs[m * 256 + lane * 4];
#pragma unroll
          for (int dd = 0; dd < 2; dd++) {
            float4 ww = w[dd]; int a = dd * 10 + m;
            acc[a] += x.x * ww.x; acc[a] += x.y * ww.y; acc[a] += x.z * ww.z; acc[a] += x.w * ww.w;
          }
        }
      }
#pragma unroll
      for (int a = 0; a < 20; a++) acc[a] = rowsum16(acc[a]);
      __syncthreads();
      if ((lane & 15) == 15) {
        int r = lane >> 4;
        float* p = &part[(wav * 4 + r) * 20];
#pragma unroll
        for (int a = 0; a < 20; a += 4) *(float4*)&p[a] = make_float4(acc[a], acc[a + 1], acc[a + 2], acc[a + 3]);
      }
      __syncthreads();
      if (tid < 160) {
        int m = tid >> 4, dloc = tid & 15, w_ = dloc >> 1, dd = dloc & 1;
        float s = 0;
#pragma unroll
        for (int r = 0; r < 4; r++) s += part[(w_ * 4 + r) * 20 + dd * 10 + m];
        int d = d16 * 16 + dloc;
        int b = (m0 + m) / 5;
        joint[(long)(m0 + m) * HH + d] = tanhf(s + tn_proj[((long)b * TSTEPS + t) * HH + d] + b_joint[d]);
      }
    }
    gsync();

    // ---- phase L: logits + per-(m,v64) exp-sum partial + local top-5 ----
    {
      int v64 = sec;
      float acc[80];
#pragma unroll
      for (int a = 0; a < 80; a++) acc[a] = 0.f;
      for (int c = 0; c < 4; c++) {
        int kc = c * 256;
        float4 w[8];
#pragma unroll
        for (int vv = 0; vv < 8; vv++) {
          int row = v64 * 64 + wav * 8 + vv;
          w[vv] = *(const float4*)&WoutT[(long)row * HH + kc + lane * 4];
        }
        __syncthreads();
        for (int f = tid; f < 640; f += NT) {
          int m = f >> 6, k4 = (f & 63) * 4;
          *(float4*)&xs[f * 4] = *(const float4*)&joint[(long)(m0 + m) * HH + kc + k4];
        }
        __syncthreads();
#pragma unroll
        for (int m = 0; m < 10; m++) {
          float4 x = *(const float4*)&xs[m * 256 + lane * 4];
#pragma unroll
          for (int vv = 0; vv < 8; vv++) {
            float4 ww = w[vv]; int a = vv * 10 + m;
            acc[a] += x.x * ww.x; acc[a] += x.y * ww.y; acc[a] += x.z * ww.z; acc[a] += x.w * ww.w;
          }
        }
      }
#pragma unroll
      for (int a = 0; a < 80; a++) acc[a] = rowsum16(acc[a]);
      __syncthreads();
      if ((lane & 15) == 15) {
        int r = lane >> 4;
        float* p = &part[(wav * 4 + r) * 80];
#pragma unroll
        for (int a = 0; a < 80; a += 4) *(float4*)&p[a] = make_float4(acc[a], acc[a + 1], acc[a + 2], acc[a + 3]);
      }
      __syncthreads();
      int npass = (wav < 2) ? 2 : 1;     // wave w: m=w; waves 0,1 also m=8,9
      for (int pass = 0; pass < npass; pass++) {
        int m = (pass == 0) ? wav : 8 + wav;
        int vloc = lane, w_ = vloc >> 3, vv = vloc & 7;
        float s = 0;
#pragma unroll
        for (int r = 0; r < 4; r++) s += part[(w_ * 4 + r) * 80 + vv * 10 + m];
        int v = v64 * 64 + vloc;
        float lg = s + b_out[v];
        float e = rowsum16(expf(lg));
        if ((lane & 15) == 15) esl[m][lane >> 4] = e;
        int mglob = m0 + m;
        float cv = lg; int ci = (mglob % 5) * 4096 + v;   // flat cand idx kp*V+v
        int toff = (mglob * 64 + v64) * 5;
#pragma unroll
        for (int r = 0; r < 5; r++) {
          float mv = cv; int mi = ci;
#pragma unroll
          for (int off2 = 1; off2 < 64; off2 <<= 1) {
            float ov = __shfl_xor(mv, off2, 64);
            int oi = __shfl_xor(mi, off2, 64);
            if (ov > mv || (ov == mv && oi < mi)) { mv = ov; mi = oi; }
          }
          if (cv == mv && ci == mi) cv = -3.0e38f;   // pop winner
          if (lane == 0) { top5v[toff + r] = mv; top5i[toff + r] = mi; }
        }
      }
      __syncthreads();
      if (tid < 10) {
        float es = ((esl[tid][0] + esl[tid][1]) + esl[tid][2]) + esl[tid][3];
        expsum_part[(m0 + tid) * 64 + v64] = es;
      }
    }
    gsync();
  }

  beam_update(TSTEPS);
  if (blk < 4 && tid < 10) { gscores[m0 + tid] = s_scores[tid]; glens[m0 + tid] = s_lens[tid]; }
  gsync();

  if (blk == 0) {
    if (tid < 40) out[1033 + tid] = gscores[tid] / (float)(glens[tid] + 1);
    if (tid < 8) {
      float bvn = -3.0e38f; int bk = 0;
      for (int k = 0; k < 5; k++) {
        float n = gscores[tid * 5 + k] / (float)(glens[tid * 5 + k] + 1);
        if (n > bvn) { bvn = n; bk = k; }
      }
      s_best[tid] = bk; s_maxn[tid] = bvn;
      out[1024 + tid] = (float)glens[tid * 5 + bk];
    }
    __syncthreads();
    if (tid == 0) {
      float s = 0;
      for (int b = 0; b < 8; b++) s += expf(s_maxn[b]);
      out[1032] = s / 8.f;
    }
    for (int cI = tid; cI < 1024; cI += NT) {
      int b = cI >> 7, pos = cI & 127;
      out[cI] = (float)preds0[(b * 5 + s_best[b]) * 128 + pos];  // after 128 updates, final buf = preds0
    }
  }
}

// ---------- launch ----------

extern "C" void kernel_launch(void* const* d_in, const int* in_sizes, int n_in,
                              void* d_out, int out_size, void* d_ws, size_t ws_size,
                              hipStream_t stream) {
  const float* tn   = (const float*)d_in[0];
  const float* E    = (const float*)d_in[1];
  const float* Wih  = (const float*)d_in[2];
  const float* Whh  = (const float*)d_in[3];
  const float* bl   = (const float*)d_in[4];
  const float* Wtn  = (const float*)d_in[5];
  const float* Wpn  = (const float*)d_in[6];
  const float* bj   = (const float*)d_in[7];
  const float* Wout = (const float*)d_in[8];
  const float* bo   = (const float*)d_in[9];
  float* out = (float*)d_out;

  unsigned int* bar = (unsigned int*)d_ws;       // 256 B reserved, zeroed below
  float* w = (float*)d_ws + 64;
  size_t off = 0;
  float* tn_proj = w + off; off += 1048576;
  float* WpnT    = w + off; off += 1048576;
  float* WoutT   = w + off; off += 4194304;
  float* joint   = w + off; off += 40960;
  float* expsum  = w + off; off += 2560;
  float* top5v   = w + off; off += 12800;
  float* h_pre0  = w + off; off += 40960;
  float* h_pre1  = w + off; off += 40960;
  float* c_pre0  = w + off; off += 40960;
  float* c_pre1  = w + off; off += 40960;
  float* h_new0  = w + off; off += 40960;
  float* h_new1  = w + off; off += 40960;
  float* c_new0  = w + off; off += 40960;
  float* c_new1  = w + off; off += 40960;
  float* gscores = w + off; off += 40;
  int* ib = (int*)(w + off);
  int* top5i  = ib; ib += 12800;
  int* preds0 = ib; ib += 5120;
  int* preds1 = ib; ib += 5120;
  int* glens  = ib; ib += 40;
  if (ws_size < (size_t)(64 + off + 23080) * 4) return;   // ~26.8 MB

  hipMemsetAsync(bar, 0, 256, stream);
  k_transp<<<dim3(32, 32), 256, 0, stream>>>(Wpn, WpnT, 1024, 1024);
  k_transp<<<dim3(128, 32), 256, 0, stream>>>(Wout, WoutT, 1024, 4096);
  k_tnproj<<<256, 256, 0, stream>>>(tn, Wtn, tn_proj);

  void* args[] = { (void*)&E, (void*)&Wih, (void*)&Whh, (void*)&bl,
                   (void*)&tn_proj, (void*)&WpnT, (void*)&bj, (void*)&WoutT, (void*)&bo,
                   (void*)&h_pre0, (void*)&h_pre1, (void*)&c_pre0, (void*)&c_pre1,
                   (void*)&h_new0, (void*)&h_new1, (void*)&c_new0, (void*)&c_new1,
                   (void*)&joint, (void*)&expsum, (void*)&top5v, (void*)&top5i,
                   (void*)&preds0, (void*)&preds1, (void*)&gscores, (void*)&glens,
                   (void*)&bar, (void*)&out };
  hipLaunchCooperativeKernel((void*)k_beam, dim3(NB), dim3(NT), args, 0, stream);
}